// Round 3
// baseline (2059.185 us; speedup 1.0000x reference)
//
#include <hip/hip_runtime.h>
#include <hip/hip_bf16.h>

// Problem constants
#define S_TOT 5184      // total sequence
#define T_TXT 64        // text tokens
#define OFF0  64        // start of image0 (32x32)
#define OFF1  1088      // start of image1 (64x64)
#define NHEAD 16
#define CH    64        // channels per head
#define HID   1024
#define BATCH 4
#define BN_TOT (BATCH*NHEAD)   // 64

typedef __attribute__((ext_vector_type(8))) short bf16x8;
typedef __attribute__((ext_vector_type(4))) float f32x4;

__device__ __forceinline__ unsigned int f2bf(float x) {
  unsigned int u = __float_as_uint(x);
  unsigned int r = u + 0x7fffu + ((u >> 16) & 1u);
  return r >> 16;   // RNE bf16 in low 16 bits
}

__device__ __forceinline__ void gload_lds16(const short* g, short* l) {
  __builtin_amdgcn_global_load_lds(
      (const __attribute__((address_space(1))) unsigned int*)g,
      (__attribute__((address_space(3))) unsigned int*)l, 16, 0, 0);
}

// ---------------- conversion kernels ----------------
__global__ __launch_bounds__(256) void cvt_bf16(const float* __restrict__ in,
                                                unsigned int* __restrict__ out, int n8) {
  const int i = blockIdx.x * 256 + threadIdx.x;
  if (i >= n8) return;
  const float4 a = ((const float4*)in)[2 * i];
  const float4 b = ((const float4*)in)[2 * i + 1];
  uint4 r;
  r.x = f2bf(a.x) | (f2bf(a.y) << 16);
  r.y = f2bf(a.z) | (f2bf(a.w) << 16);
  r.z = f2bf(b.x) | (f2bf(b.y) << 16);
  r.w = f2bf(b.z) | (f2bf(b.w) << 16);
  ((uint4*)out)[i] = r;
}

// in: f32 [R][Cn] row-major -> out: bf16 [Cn][R]
__global__ void cvt_T(const float* __restrict__ in, short* __restrict__ out,
                      const int R, const int Cn) {
  __shared__ float t[32][33];
  const int bx = blockIdx.x * 32, by = blockIdx.y * 32;
  const int tx = threadIdx.x, ty = threadIdx.y;
#pragma unroll
  for (int ph = 0; ph < 4; ++ph)
    t[ty + ph * 8][tx] = in[(size_t)(by + ty + ph * 8) * Cn + bx + tx];
  __syncthreads();
#pragma unroll
  for (int ph = 0; ph < 4; ++ph)
    out[(size_t)(bx + ty + ph * 8) * R + by + tx] = (short)f2bf(t[tx][ty + ph * 8]);
}

// ---------------- bf16 MFMA GEMM: C = A(MxK) * BT(NxK)^T + bias ----------------
// EPI==0: f32 store to C.  EPI==1: scatter into q/k/v f32 buffers [bh][s][64] (q * 0.125).
template<int EPI>
__global__ __launch_bounds__(256) void gemm_mfma(
    const short* __restrict__ A, const short* __restrict__ BT,
    const float* __restrict__ bias, float* __restrict__ C,
    float* __restrict__ qbuf, float* __restrict__ kbuf, float* __restrict__ vbuf,
    const int M, const int N, const int K)
{
  __shared__ short As[128 * 32];
  __shared__ short Bs[128 * 32];
  const int tid = threadIdx.x;
  const int w = tid >> 6, l = tid & 63;
  const int bm = blockIdx.x * 128, bn = blockIdx.y * 128;
  const int wr = w >> 1, wc = w & 1;
  const int lr = l & 15, lk = (l >> 4) * 8;

  const short* aSrc = A + (size_t)(bm + w * 32 + (l >> 2)) * K + (l & 3) * 8;
  const short* bSrc = BT + (size_t)(bn + w * 32 + (l >> 2)) * K + (l & 3) * 8;
  short* aDst = As + w * 32 * 32;
  short* bDst = Bs + w * 32 * 32;

  f32x4 acc[4][4];
#pragma unroll
  for (int m = 0; m < 4; ++m)
#pragma unroll
    for (int n = 0; n < 4; ++n) acc[m][n] = (f32x4){0.f, 0.f, 0.f, 0.f};

  for (int k0 = 0; k0 < K; k0 += 32) {
    gload_lds16(aSrc + k0,            aDst);
    gload_lds16(aSrc + k0 + 16 * K,   aDst + 16 * 32);
    gload_lds16(bSrc + k0,            bDst);
    gload_lds16(bSrc + k0 + 16 * K,   bDst + 16 * 32);
    __syncthreads();
    bf16x8 af[4], bfr[4];
#pragma unroll
    for (int m = 0; m < 4; ++m)
      af[m] = *(const bf16x8*)&As[(wr * 64 + m * 16 + lr) * 32 + lk];
#pragma unroll
    for (int n = 0; n < 4; ++n)
      bfr[n] = *(const bf16x8*)&Bs[(wc * 64 + n * 16 + lr) * 32 + lk];
#pragma unroll
    for (int m = 0; m < 4; ++m)
#pragma unroll
      for (int n = 0; n < 4; ++n)
        acc[m][n] = __builtin_amdgcn_mfma_f32_16x16x32_bf16(af[m], bfr[n], acc[m][n], 0, 0, 0);
    __syncthreads();
  }

#pragma unroll
  for (int m = 0; m < 4; ++m) {
    const int row0 = bm + wr * 64 + m * 16 + (l >> 4) * 4;
#pragma unroll
    for (int n = 0; n < 4; ++n) {
      const int col = bn + wc * 64 + n * 16 + lr;
      const float bv = bias[col];
      if constexpr (EPI == 0) {
#pragma unroll
        for (int i = 0; i < 4; ++i)
          C[(size_t)(row0 + i) * N + col] = acc[m][n][i] + bv;
      } else {
        const int type = col >> 10;            // 0=q 1=k 2=v
        const int head = (col & 1023) >> 6;
        const int chn  = col & 63;
        float* dst = (type == 0) ? qbuf : ((type == 1) ? kbuf : vbuf);
        const float sc = (type == 0) ? 0.125f : 1.f;
#pragma unroll
        for (int i = 0; i < 4; ++i) {
          const int row = row0 + i;
          const int b_ = row / S_TOT;
          const int s_ = row - b_ * S_TOT;
          dst[(((size_t)(b_ * NHEAD + head)) * S_TOT + s_) * CH + chn] = (acc[m][n][i] + bv) * sc;
        }
      }
    }
  }
}

// ---------------- online-softmax attention helpers (2 lanes per query) ----------------
// Each thread owns 32 channels (half=0 -> ch 0..31, half=1 -> ch 32..63).
__device__ __forceinline__ float dot32(const float4* __restrict__ q, const float* __restrict__ kp) {
  const float4* k4 = (const float4*)kp;
  float s = 0.f;
#pragma unroll
  for (int i = 0; i < 8; ++i) {
    float4 a = q[i]; float4 b = k4[i];
    s = fmaf(a.x, b.x, s); s = fmaf(a.y, b.y, s);
    s = fmaf(a.z, b.z, s); s = fmaf(a.w, b.w, s);
  }
  return s;
}

// defer-max online update (THR=8): p = exp(s-m) bounded by e^8
__device__ __forceinline__ void upd(float s, const float* __restrict__ vp,
                                    float& m, float& l, float4* __restrict__ acc) {
  if (s > m + 8.f) {
    const float r = __expf(m - s);
    l *= r;
#pragma unroll
    for (int i = 0; i < 8; ++i) {
      acc[i].x *= r; acc[i].y *= r; acc[i].z *= r; acc[i].w *= r;
    }
    m = s;
  }
  const float p = __expf(s - m);
  l += p;
  const float4* v4 = (const float4*)vp;
#pragma unroll
  for (int i = 0; i < 8; ++i) {
    float4 v = v4[i];
    acc[i].x = fmaf(p, v.x, acc[i].x);
    acc[i].y = fmaf(p, v.y, acc[i].y);
    acc[i].z = fmaf(p, v.z, acc[i].z);
    acc[i].w = fmaf(p, v.w, acc[i].w);
  }
}

// out-of-bounds window slot: score exactly 0, no value contribution
__device__ __forceinline__ void upd0(float& m, float& l, float4* __restrict__ acc) {
  if (0.f > m + 8.f) {
    const float r = __expf(m);
    l *= r;
#pragma unroll
    for (int i = 0; i < 8; ++i) {
      acc[i].x *= r; acc[i].y *= r; acc[i].z *= r; acc[i].w *= r;
    }
    m = 0.f;
  }
  l += __expf(-m);
}

__device__ __forceinline__ void store_half_bf16(short* ctx, size_t base, const float4* acc, float inv) {
  unsigned int* cp = (unsigned int*)(ctx + base);
#pragma unroll
  for (int i = 0; i < 8; ++i) {
    cp[2 * i]     = f2bf(acc[i].x * inv) | (f2bf(acc[i].y * inv) << 16);
    cp[2 * i + 1] = f2bf(acc[i].z * inv) | (f2bf(acc[i].w * inv) << 16);
  }
}

// ---------------- attention: text queries ----------------
__global__ __launch_bounds__(256, 4) void attn_text(
    const float* __restrict__ qb, const float* __restrict__ kb, const float* __restrict__ vb,
    const float* __restrict__ mask, short* __restrict__ ctx)
{
  const int t = blockIdx.x * 256 + threadIdx.x;
  const int half = t & 1;
  const int pair = t >> 1;
  const int bh = pair >> 6;
  const int tq = pair & 63;
  const int b_ = bh >> 4, head = bh & 15;

  float4 q[8];
  const float4* qp = (const float4*)(qb + ((size_t)bh * S_TOT + tq) * CH + half * 32);
#pragma unroll
  for (int i = 0; i < 8; ++i) q[i] = qp[i];

  float m = -1e30f, l = 0.f;
  float4 acc[8];
#pragma unroll
  for (int i = 0; i < 8; ++i) acc[i] = make_float4(0.f, 0.f, 0.f, 0.f);

  const float* mrow = mask + ((size_t)b_ * S_TOT + tq) * T_TXT;
  const float* kt = kb + (size_t)bh * S_TOT * CH + half * 32;
  const float* vt = vb + (size_t)bh * S_TOT * CH + half * 32;
  for (int j = 0; j < T_TXT; ++j) {
    float d = dot32(q, kt + j * CH);
    d += __shfl_xor(d, 1);
    float mv = mrow[j];
    d = d * mv - 10000.f * (1.f - mv);
    upd(d, vt + j * CH, m, l, acc);
  }
  store_half_bf16(ctx, ((size_t)(b_ * S_TOT + tq)) * HID + head * CH + half * 32, acc, 1.f / l);
}

// ---------------- attention: image0 queries (32x32, 9x9 causal) ----------------
__global__ __launch_bounds__(256, 4) void attn_img0(
    const float* __restrict__ qb, const float* __restrict__ kb, const float* __restrict__ vb,
    const float* __restrict__ mask, short* __restrict__ ctx)
{
  const int t = blockIdx.x * 256 + threadIdx.x;
  const int half = t & 1;
  const int pair = t >> 1;
  const int bh = pair >> 10;
  const int p = pair & 1023;
  const int qi = p >> 5, qj = p & 31;
  const int s = OFF0 + p;
  const int b_ = bh >> 4, head = bh & 15;

  float4 q[8];
  const float4* qp = (const float4*)(qb + ((size_t)bh * S_TOT + s) * CH + half * 32);
#pragma unroll
  for (int i = 0; i < 8; ++i) q[i] = qp[i];

  float m = -1e30f, l = 0.f;
  float4 acc[8];
#pragma unroll
  for (int i = 0; i < 8; ++i) acc[i] = make_float4(0.f, 0.f, 0.f, 0.f);

  const float* mrow = mask + ((size_t)b_ * S_TOT + s) * T_TXT;
  const float* kt = kb + (size_t)bh * S_TOT * CH + half * 32;
  const float* vt = vb + (size_t)bh * S_TOT * CH + half * 32;
  for (int j = 0; j < T_TXT; ++j) {
    float d = dot32(q, kt + j * CH);
    d += __shfl_xor(d, 1);
    float mv = mrow[j];
    d = d * mv - 10000.f * (1.f - mv);
    upd(d, vt + j * CH, m, l, acc);
  }
  const float* k0 = kt + OFF0 * CH;
  const float* v0 = vt + OFF0 * CH;
  for (int di = -4; di <= 0; ++di) {
    const int djmax = (di == 0) ? 0 : 4;
    const int ki = qi + di;
    for (int dj = -4; dj <= djmax; ++dj) {
      const int kj = qj + dj;
      if ((unsigned)ki < 32u && (unsigned)kj < 32u) {
        const int off = (ki * 32 + kj) * CH;
        float d = dot32(q, k0 + off);
        d += __shfl_xor(d, 1);
        upd(d, v0 + off, m, l, acc);
      } else {
        upd0(m, l, acc);
      }
    }
  }
  store_half_bf16(ctx, ((size_t)(b_ * S_TOT + s)) * HID + head * CH + half * 32, acc, 1.f / l);
}

// ---------------- attention: image1 queries (64x64; 7x7 over k0 + 9x9 causal over k1) ----------------
__global__ __launch_bounds__(256, 4) void attn_img1(
    const float* __restrict__ qb, const float* __restrict__ kb, const float* __restrict__ vb,
    const float* __restrict__ mask, short* __restrict__ ctx)
{
  const int t = blockIdx.x * 256 + threadIdx.x;
  const int half = t & 1;
  const int pair = t >> 1;
  const int bh = pair >> 12;
  const int p = pair & 4095;
  const int qi = p >> 6, qj = p & 63;
  const int s = OFF1 + p;
  const int b_ = bh >> 4, head = bh & 15;

  float4 q[8];
  const float4* qp = (const float4*)(qb + ((size_t)bh * S_TOT + s) * CH + half * 32);
#pragma unroll
  for (int i = 0; i < 8; ++i) q[i] = qp[i];

  float m = -1e30f, l = 0.f;
  float4 acc[8];
#pragma unroll
  for (int i = 0; i < 8; ++i) acc[i] = make_float4(0.f, 0.f, 0.f, 0.f);

  const float* mrow = mask + ((size_t)b_ * S_TOT + s) * T_TXT;
  const float* kt = kb + (size_t)bh * S_TOT * CH + half * 32;
  const float* vt = vb + (size_t)bh * S_TOT * CH + half * 32;
  for (int j = 0; j < T_TXT; ++j) {
    float d = dot32(q, kt + j * CH);
    d += __shfl_xor(d, 1);
    float mv = mrow[j];
    d = d * mv - 10000.f * (1.f - mv);
    upd(d, vt + j * CH, m, l, acc);
  }
  // 7x7 full window over k0 (32x32), base = (qi/2, qj/2)
  const float* k0 = kt + OFF0 * CH;
  const float* v0 = vt + OFF0 * CH;
  const int ki0 = qi >> 1, kj0 = qj >> 1;
  for (int di = -3; di <= 3; ++di) {
    const int ki = ki0 + di;
    for (int dj = -3; dj <= 3; ++dj) {
      const int kj = kj0 + dj;
      if ((unsigned)ki < 32u && (unsigned)kj < 32u) {
        const int off = (ki * 32 + kj) * CH;
        float d = dot32(q, k0 + off);
        d += __shfl_xor(d, 1);
        upd(d, v0 + off, m, l, acc);
      } else {
        upd0(m, l, acc);
      }
    }
  }
  // 9x9 causal window over k1 (64x64)
  const float* k1 = kt + OFF1 * CH;
  const float* v1 = vt + OFF1 * CH;
  for (int di = -4; di <= 0; ++di) {
    const int djmax = (di == 0) ? 0 : 4;
    const int ki = qi + di;
    for (int dj = -4; dj <= djmax; ++dj) {
      const int kj = qj + dj;
      if ((unsigned)ki < 64u && (unsigned)kj < 64u) {
        const int off = (ki * 64 + kj) * CH;
        float d = dot32(q, k1 + off);
        d += __shfl_xor(d, 1);
        upd(d, v1 + off, m, l, acc);
      } else {
        upd0(m, l, acc);
      }
    }
  }
  store_half_bf16(ctx, ((size_t)(b_ * S_TOT + s)) * HID + head * CH + half * 32, acc, 1.f / l);
}

// ---------------- launch ----------------
extern "C" void kernel_launch(void* const* d_in, const int* in_sizes, int n_in,
                              void* d_out, int out_size, void* d_ws, size_t ws_size,
                              hipStream_t stream) {
  const float* hidden = (const float*)d_in[0];
  const float* mask   = (const float*)d_in[1];
  const float* w_qkv  = (const float*)d_in[2];
  const float* b_qkv  = (const float*)d_in[3];
  const float* w_out  = (const float*)d_in[4];
  const float* b_out  = (const float*)d_in[5];
  float* out = (float*)d_out;

  const size_t NB = (size_t)BN_TOT * S_TOT * CH;   // 21,233,664 elements
  float* qbuf = (float*)d_ws;
  float* kbuf = qbuf + NB;
  float* vbuf = kbuf + NB;
  short* hbf   = (short*)(vbuf + NB);   // hidden bf16; later ALIASED as ctx bf16
  short* wqkvT = hbf + NB;              // [3072][1024] bf16
  short* woutT = wqkvT + (size_t)3072 * 1024;  // [1024][1024] bf16

  const int M = BATCH * S_TOT;   // 20736

  // 0) conversions
  cvt_bf16<<<(int)((NB / 8 + 255) / 256), 256, 0, stream>>>(hidden, (unsigned int*)hbf, (int)(NB / 8));
  cvt_T<<<dim3(3072 / 32, 1024 / 32), dim3(32, 8), 0, stream>>>(w_qkv, wqkvT, 1024, 3072);
  cvt_T<<<dim3(1024 / 32, 1024 / 32), dim3(32, 8), 0, stream>>>(w_out, woutT, 1024, 1024);

  // 1) QKV projection (bf16 MFMA) with q/k/v scatter epilogue
  gemm_mfma<1><<<dim3(M / 128, 3072 / 128), 256, 0, stream>>>(
      hbf, wqkvT, b_qkv, nullptr, qbuf, kbuf, vbuf, M, 3072, 1024);

  // 2) attention (online softmax, 2 lanes/query, no LDS; bf16 ctx output)
  short* ctx = hbf;
  attn_text<<<(BN_TOT * T_TXT * 2) / 256, 256, 0, stream>>>(qbuf, kbuf, vbuf, mask, ctx);
  attn_img0<<<(BN_TOT * 1024 * 2) / 256, 256, 0, stream>>>(qbuf, kbuf, vbuf, mask, ctx);
  attn_img1<<<(BN_TOT * 4096 * 2) / 256, 256, 0, stream>>>(qbuf, kbuf, vbuf, mask, ctx);

  // 3) output projection (bf16 MFMA)
  gemm_mfma<0><<<dim3(M / 128, 1024 / 128), 256, 0, stream>>>(
      ctx, woutT, b_out, out, nullptr, nullptr, nullptr, M, 1024, 1024);
}